// Round 1
// baseline (586.394 us; speedup 1.0000x reference)
//
#include <hip/hip_runtime.h>
#include <math.h>

// Problem constants (fixed by the reference)
constexpr int kT = 500000;     // history length
constexpr int kQ = 256;        // feature size
constexpr int kH = 256;        // hidden size
constexpr int kK = 32;         // attn_k
constexpr int kNB1 = 256;      // phase-1 top-k blocks
constexpr int kCHUNK = (kT + kNB1 - 1) / kNB1;  // 1954
constexpr int kNC = kNB1 * kK; // 8192 merge candidates

__device__ __forceinline__ void store4(float* __restrict__ dst, float4 v) {
  // out region is offset by +1 float -> 16B-misaligned; use dword stores.
  dst[0] = v.x; dst[1] = v.y; dst[2] = v.z; dst[3] = v.w;
}

// Fused: copy qs -> out[1 ..], append ques_h as row kT, compute alpha = qs @ ques_h.
// One wave (64 lanes) per row; lane l handles float4 [4l..4l+3].
__global__ __launch_bounds__(256) void k_copy_qs_alpha(
    const float* __restrict__ qs, const float* __restrict__ qh,
    float* __restrict__ out, float* __restrict__ alpha) {
  const int lane = threadIdx.x & 63;
  const int wid  = (int)((blockIdx.x * blockDim.x + threadIdx.x) >> 6);
  const int nw   = (int)((gridDim.x * blockDim.x) >> 6);
  const float4 q4 = ((const float4*)qh)[lane];
  for (int t = wid; t <= kT; t += nw) {
    const float4* src = (t < kT) ? ((const float4*)(qs + (size_t)t * kQ))
                                 : ((const float4*)qh);
    float4 v = src[lane];
    store4(out + 1 + (size_t)t * kQ + lane * 4, v);
    if (t < kT) {
      float d = v.x * q4.x + v.y * q4.y + v.z * q4.z + v.w * q4.w;
#pragma unroll
      for (int off = 32; off; off >>= 1) d += __shfl_xor(d, off);
      if (lane == 0) alpha[t] = d;
    }
  }
}

// Plain copy hs -> hs_new rows [0, kT). Runs LAST (overwrites scratch region).
__global__ __launch_bounds__(256) void k_copy_hs(
    const float* __restrict__ hs, float* __restrict__ out) {
  const size_t i      = (size_t)blockIdx.x * blockDim.x + threadIdx.x;
  const size_t stride = (size_t)gridDim.x * blockDim.x;
  float* base = out + 1 + (size_t)(kT + 1) * kQ;
  const float4* src = (const float4*)hs;
  const size_t nv = (size_t)kT * (kH / 4);
  for (size_t v = i; v < nv; v += stride) {
    store4(base + v * 4, src[v]);
  }
}

// Phase 1: each block extracts its chunk's top-32 (val, global idx) from LDS.
__global__ __launch_bounds__(256) void k_topk1(
    const float* __restrict__ alpha, float* __restrict__ candV,
    int* __restrict__ candI) {
  __shared__ float sv[kCHUNK];
  __shared__ float rv[4];
  __shared__ int ri[4];
  const int tid = threadIdx.x;
  const int base = blockIdx.x * kCHUNK;
  for (int i = tid; i < kCHUNK; i += 256) {
    int g = base + i;
    sv[i] = (g < kT) ? alpha[g] : -INFINITY;
  }
  __syncthreads();
  for (int k = 0; k < kK; ++k) {
    float bv = -INFINITY; int bi = -1;
    for (int i = tid; i < kCHUNK; i += 256) {
      float v = sv[i];
      if (v > bv) { bv = v; bi = i; }
    }
#pragma unroll
    for (int off = 32; off; off >>= 1) {
      float ov = __shfl_xor(bv, off);
      int   oi = __shfl_xor(bi, off);
      if (ov > bv || (ov == bv && oi != -1 && (bi == -1 || oi < bi))) { bv = ov; bi = oi; }
    }
    if ((tid & 63) == 0) { rv[tid >> 6] = bv; ri[tid >> 6] = bi; }
    __syncthreads();
    if (tid == 0) {
      float fv = rv[0]; int fi = ri[0];
      for (int j = 1; j < 4; ++j)
        if (rv[j] > fv || (rv[j] == fv && ri[j] != -1 && (fi == -1 || ri[j] < fi))) {
          fv = rv[j]; fi = ri[j];
        }
      candV[blockIdx.x * kK + k] = fv;
      candI[blockIdx.x * kK + k] = (fi >= 0) ? (base + fi) : 0;
      if (fi >= 0) sv[fi] = -INFINITY;
    }
    __syncthreads();
  }
}

// Phase 2 + attention + pred: single block merges 8192 candidates -> top-32,
// softmax, attn_h = w @ hs[idx], pred = W_s @ [ques_h, attn_h] + b_s.
__global__ __launch_bounds__(256) void k_attn(
    const float* __restrict__ candV, const int* __restrict__ candI,
    const float* __restrict__ hs, const float* __restrict__ qh,
    const float* __restrict__ Ws, const float* __restrict__ bs,
    float* __restrict__ out) {
  __shared__ float sv[kNC];
  __shared__ float rv[4];
  __shared__ int ri[4];
  __shared__ float topv[kK];
  __shared__ int topi[kK];
  __shared__ float w[kK];
  __shared__ float red[256];
  const int tid = threadIdx.x;
  for (int i = tid; i < kNC; i += 256) sv[i] = candV[i];
  __syncthreads();
  for (int k = 0; k < kK; ++k) {
    float bv = -INFINITY; int bi = -1;
    for (int i = tid; i < kNC; i += 256) {
      float v = sv[i];
      if (v > bv) { bv = v; bi = i; }
    }
#pragma unroll
    for (int off = 32; off; off >>= 1) {
      float ov = __shfl_xor(bv, off);
      int   oi = __shfl_xor(bi, off);
      if (ov > bv || (ov == bv && oi != -1 && (bi == -1 || oi < bi))) { bv = ov; bi = oi; }
    }
    if ((tid & 63) == 0) { rv[tid >> 6] = bv; ri[tid >> 6] = bi; }
    __syncthreads();
    if (tid == 0) {
      float fv = rv[0]; int fi = ri[0];
      for (int j = 1; j < 4; ++j)
        if (rv[j] > fv || (rv[j] == fv && ri[j] != -1 && (fi == -1 || ri[j] < fi))) {
          fv = rv[j]; fi = ri[j];
        }
      topv[k] = fv;
      topi[k] = candI[fi];
      sv[fi] = -INFINITY;
    }
    __syncthreads();
  }
  if (tid == 0) {
    float m = topv[0];
    for (int j = 1; j < kK; ++j) m = fmaxf(m, topv[j]);
    float s = 0.f;
    for (int j = 0; j < kK; ++j) { w[j] = expf(topv[j] - m); s += w[j]; }
    float inv = 1.f / s;
    for (int j = 0; j < kK; ++j) w[j] *= inv;
  }
  __syncthreads();
  float a = 0.f;
#pragma unroll
  for (int j = 0; j < kK; ++j) a += w[j] * hs[(size_t)topi[j] * kH + tid];
  // pred reduction over 512 terms: tid covers ques_h half and attn half
  red[tid] = Ws[tid] * qh[tid] + Ws[kQ + tid] * a;
  __syncthreads();
  for (int s = 128; s; s >>= 1) {
    if (tid < s) red[tid] += red[tid + s];
    __syncthreads();
  }
  if (tid == 0) out[0] = red[0] + bs[0];
}

// GRU matvecs: one wave per output row r of gi/gh.
__global__ __launch_bounds__(64) void k_gru1(
    const float* __restrict__ Wih, const float* __restrict__ Whh,
    const float* __restrict__ bih, const float* __restrict__ bhh,
    const float* __restrict__ qh, const float* __restrict__ hs,
    const float* __restrict__ score, float* __restrict__ gi,
    float* __restrict__ gh) {
  const int r = blockIdx.x;
  const int lane = threadIdx.x;
  const int off = (score[0] >= 0.5f) ? 0 : kQ;  // x = [qh*ge, qh*(1-ge)]
  const float* hprev = hs + (size_t)(kT - 1) * kH;
  float4 q4 = ((const float4*)qh)[lane];
  float4 h4 = ((const float4*)hprev)[lane];
  float4 wi = ((const float4*)(Wih + (size_t)r * (2 * kQ) + off))[lane];
  float4 wh = ((const float4*)(Whh + (size_t)r * kH))[lane];
  float di = wi.x * q4.x + wi.y * q4.y + wi.z * q4.z + wi.w * q4.w;
  float dh = wh.x * h4.x + wh.y * h4.y + wh.z * h4.z + wh.w * h4.w;
#pragma unroll
  for (int o = 32; o; o >>= 1) {
    di += __shfl_xor(di, o);
    dh += __shfl_xor(dh, o);
  }
  if (lane == 0) {
    gi[r] = di + bih[r];
    gh[r] = dh + bhh[r];
  }
}

// GRU gates + write hs_new row kT.
__global__ __launch_bounds__(256) void k_gru2(
    const float* __restrict__ gi, const float* __restrict__ gh,
    const float* __restrict__ hs, float* __restrict__ out) {
  const int i = threadIdx.x;
  const float* hprev = hs + (size_t)(kT - 1) * kH;
  float rr = 1.f / (1.f + expf(-(gi[i] + gh[i])));
  float z  = 1.f / (1.f + expf(-(gi[kH + i] + gh[kH + i])));
  float n  = tanhf(gi[2 * kH + i] + rr * gh[2 * kH + i]);
  float hn = (1.f - z) * n + z * hprev[i];
  out[1 + (size_t)(kT + 1) * kQ + (size_t)kT * kH + i] = hn;
}

extern "C" void kernel_launch(void* const* d_in, const int* in_sizes, int n_in,
                              void* d_out, int out_size, void* d_ws, size_t ws_size,
                              hipStream_t stream) {
  const float* qh    = (const float*)d_in[0];
  const float* score = (const float*)d_in[1];
  const float* qs    = (const float*)d_in[2];
  const float* hs    = (const float*)d_in[3];
  const float* Wih   = (const float*)d_in[4];
  const float* Whh   = (const float*)d_in[5];
  const float* bih   = (const float*)d_in[6];
  const float* bhh   = (const float*)d_in[7];
  const float* Ws    = (const float*)d_in[8];
  const float* bs    = (const float*)d_in[9];
  float* out = (float*)d_out;

  // Scratch lives at the START of the hs_new output region (~2.1 MB used of
  // 512 MB). It is consumed by topk/attn/gru, then fully overwritten by the
  // final k_copy_hs. No dependence on ws_size; deterministic every call.
  float* S     = out + 1 + (size_t)(kT + 1) * kQ;
  float* alpha = S;                      // kT floats
  float* candV = S + kT;                 // kNC floats
  int*   candI = (int*)(S + kT + kNC);   // kNC ints
  float* gi    = S + kT + 2 * kNC;       // 768 floats
  float* gh    = gi + 3 * kH;            // 768 floats

  hipLaunchKernelGGL(k_copy_qs_alpha, dim3(2048), dim3(256), 0, stream,
                     qs, qh, out, alpha);
  hipLaunchKernelGGL(k_topk1, dim3(kNB1), dim3(256), 0, stream,
                     alpha, candV, candI);
  hipLaunchKernelGGL(k_attn, dim3(1), dim3(256), 0, stream,
                     candV, candI, hs, qh, Ws, bs, out);
  hipLaunchKernelGGL(k_gru1, dim3(3 * kH), dim3(64), 0, stream,
                     Wih, Whh, bih, bhh, qh, hs, score, gi, gh);
  hipLaunchKernelGGL(k_gru2, dim3(1), dim3(256), 0, stream,
                     gi, gh, hs, out);
  hipLaunchKernelGGL(k_copy_hs, dim3(2048), dim3(256), 0, stream,
                     hs, out);
}